// Round 1
// baseline (106.261 us; speedup 1.0000x reference)
//
#include <hip/hip_runtime.h>

#define BATCH 16384
#define NPTS  500
#define NOBJ  30
#define EPW   2    // batch elements per wave
#define WPB   4    // waves per block
#define NBLK  (BATCH / (EPW * WPB))   // 2048 blocks = 8 blocks/CU

typedef float v2f __attribute__((ext_vector_type(2)));

// raw v_sqrt_f32 (1 ULP), no IEEE denormal-fixup sequence
__device__ __forceinline__ float fsqrt(float x) {
    return __builtin_amdgcn_sqrtf(x);
}

__global__ __launch_bounds__(256) void add_loss_fused(
    const float* __restrict__ pred_r,   // (B,4)
    const float* __restrict__ pred_t,   // (B,3)
    const float* __restrict__ gt_r,     // (B,4)
    const float* __restrict__ gt_t,     // (B,3)
    const int*   __restrict__ obj_ids,  // (B,)
    const float* __restrict__ points,   // (NOBJ, NPTS, 3)
    float* __restrict__ partial,        // (NBLK,)
    unsigned int* __restrict__ counter, // zeroed by memset node each launch
    float* __restrict__ out)            // scalar
{
    const int wave  = threadIdx.x >> 6;
    const int lane  = threadIdx.x & 63;
    const int gwave = blockIdx.x * WPB + wave;
    const int b0    = gwave * EPW;

    // ---- packed (elem0, elem1) quaternion -> D = Rp - Rg, via v_pk_*_f32 ----
    const float4 qp0 = ((const float4*)pred_r)[b0 + 0];
    const float4 qp1 = ((const float4*)pred_r)[b0 + 1];
    const float4 qg0 = ((const float4*)gt_r)[b0 + 0];
    const float4 qg1 = ((const float4*)gt_r)[b0 + 1];

    v2f pw = {qp0.x, qp1.x}, px = {qp0.y, qp1.y}, py = {qp0.z, qp1.z}, pz = {qp0.w, qp1.w};
    v2f gw = {qg0.x, qg1.x}, gx = {qg0.y, qg1.y}, gy = {qg0.z, qg1.z}, gz = {qg0.w, qg1.w};

    v2f d00 = 2.f*((gy*gy + gz*gz) - (py*py + pz*pz));
    v2f d01 = 2.f*((px*py - pw*pz) - (gx*gy - gw*gz));
    v2f d02 = 2.f*((px*pz + pw*py) - (gx*gz + gw*gy));
    v2f d10 = 2.f*((px*py + pw*pz) - (gx*gy + gw*gz));
    v2f d11 = 2.f*((gx*gx + gz*gz) - (px*px + pz*pz));
    v2f d12 = 2.f*((py*pz - pw*px) - (gy*gz - gw*gx));
    v2f d20 = 2.f*((px*pz - pw*py) - (gx*gz - gw*gy));
    v2f d21 = 2.f*((py*pz + pw*px) - (gy*gz + gw*gx));
    v2f d22 = 2.f*((gx*gx + gy*gy) - (px*px + py*py));

    // ---- packed t-diff: 6 consecutive floats per array, float2 loads ----
    // byte offset = 12*b0 = 24*gwave -> 8B aligned
    const float2* PT2 = (const float2*)(pred_t + 3*b0);
    const float2* GT2 = (const float2*)(gt_t  + 3*b0);
    float2 ta = PT2[0], tb = PT2[1], tc = PT2[2];
    float2 ua = GT2[0], ub = GT2[1], uc = GT2[2];
    v2f tdx = { ta.x - ua.x, tb.y - ub.y };
    v2f tdy = { ta.y - ua.y, tc.x - uc.x };
    v2f tdz = { tb.x - ub.x, tc.y - uc.y };

    v2f tq = tdx*tdx + tdy*tdy + tdz*tdz;
    const float acc_trans = fsqrt(tq.x) + fsqrt(tq.y);   // wave-uniform

    const int obj0 = obj_ids[b0 + 0];
    const int obj1 = obj_ids[b0 + 1];

    v2f sacc = {0.f, 0.f};

    #pragma unroll
    for (int e = 0; e < EPW; ++e) {
        const float D00 = d00[e], D01 = d01[e], D02 = d02[e];
        const float D10 = d10[e], D11 = d11[e], D12 = d12[e];
        const float D20 = d20[e], D21 = d21[e], D22 = d22[e];
        const float TX = tdx[e], TY = tdy[e], TZ = tdz[e];
        const int obj = e ? obj1 : obj0;
        // object row = 1500 floats = 6000 B (16-divisible -> float4-aligned)
        const float4* __restrict__ P4 = (const float4*)(points + (size_t)obj * (NPTS*3));

        // 500 points = 125 groups of 4 points (3 float4 per group)
        #pragma unroll
        for (int t = 0; t < 2; ++t) {
            const int g = t*64 + lane;
            if (t == 0 || lane < 61) {
                float4 a  = P4[3*g+0];
                float4 b4 = P4[3*g+1];
                float4 c  = P4[3*g+2];
                // pair 0 = points {0,1}, pair 1 = points {2,3} of the group
                v2f xs[2] = { {a.x, a.w},  {b4.z, c.y} };
                v2f ys[2] = { {a.y, b4.x}, {b4.w, c.z} };
                v2f zs[2] = { {a.z, b4.y}, {c.x, c.w} };
                #pragma unroll
                for (int j = 0; j < 2; ++j) {
                    v2f x = xs[j], y = ys[j], z = zs[j];
                    v2f vx = D00*x + D01*y + D02*z;
                    v2f vy = D10*x + D11*y + D12*z;
                    v2f vz = D20*x + D21*y + D22*z;
                    v2f r  = vx*vx + vy*vy + vz*vz;
                    r.x = fsqrt(r.x); r.y = fsqrt(r.y);
                    sacc += r;                          // v_pk_add_f32
                    v2f ax = vx + TX, ay = vy + TY, az = vz + TZ;
                    v2f r2 = ax*ax + ay*ay + az*az;
                    r2.x = fsqrt(r2.x); r2.y = fsqrt(r2.y);
                    sacc += r2;                         // v_pk_add_f32
                }
            }
        }
    }

    float acc_pts = sacc.x + sacc.y;
    #pragma unroll
    for (int off = 32; off > 0; off >>= 1)
        acc_pts += __shfl_down(acc_pts, off, 64);

    __shared__ float red[WPB];
    if (lane == 0)
        red[wave] = acc_pts * (1.0f / NPTS) + acc_trans;
    __syncthreads();

    // ---- fused final reduction: last-block-done (device-scope for XCD safety) ----
    __shared__ bool isLast;
    if (threadIdx.x == 0) {
        float bsum = red[0] + red[1] + red[2] + red[3];
        __hip_atomic_store(&partial[blockIdx.x], bsum,
                           __ATOMIC_RELAXED, __HIP_MEMORY_SCOPE_AGENT);
        unsigned prev = __hip_atomic_fetch_add(counter, 1u,
                           __ATOMIC_ACQ_REL, __HIP_MEMORY_SCOPE_AGENT);
        isLast = (prev == NBLK - 1);
    }
    __syncthreads();

    if (isLast) {
        float s = 0.f;
        #pragma unroll
        for (int k = 0; k < NBLK / 256; ++k)
            s += __hip_atomic_load(&partial[k*256 + (int)threadIdx.x],
                                   __ATOMIC_RELAXED, __HIP_MEMORY_SCOPE_AGENT);
        #pragma unroll
        for (int off = 32; off > 0; off >>= 1)
            s += __shfl_down(s, off, 64);
        __shared__ float red2[WPB];
        if (lane == 0) red2[wave] = s;
        __syncthreads();
        if (threadIdx.x == 0)
            out[0] = (red2[0] + red2[1] + red2[2] + red2[3]) * (1.0f / BATCH);
    }
}

extern "C" void kernel_launch(void* const* d_in, const int* in_sizes, int n_in,
                              void* d_out, int out_size, void* d_ws, size_t ws_size,
                              hipStream_t stream) {
    const float* pred_r  = (const float*)d_in[0];
    const float* pred_t  = (const float*)d_in[1];
    const float* gt_r    = (const float*)d_in[2];
    const float* gt_t    = (const float*)d_in[3];
    const int*   obj_ids = (const int*)d_in[4];
    const float* points  = (const float*)d_in[5];
    float* out     = (float*)d_out;
    float* partial = (float*)d_ws;                                   // 2048 floats
    unsigned int* counter = (unsigned int*)((char*)d_ws + NBLK * sizeof(float));

    // workspace is poisoned by the harness each iteration -> must re-zero counter
    hipMemsetAsync(counter, 0, sizeof(unsigned int), stream);

    add_loss_fused<<<NBLK, 256, 0, stream>>>(
        pred_r, pred_t, gt_r, gt_t, obj_ids, points, partial, counter, out);
}

// Round 2
// 72.168 us; speedup vs baseline: 1.4724x; 1.4724x over previous
//
#include <hip/hip_runtime.h>

#define BATCH 16384
#define NPTS  500
#define NOBJ  30
#define EPW   2    // batch elements per wave
#define WPB   4    // waves per block
#define NBLK  (BATCH / (EPW * WPB))   // 2048 blocks = 8 blocks/CU = 32 waves/CU (one generation)

typedef float v2f __attribute__((ext_vector_type(2)));

// raw v_sqrt_f32 (1 ULP), no IEEE denormal-fixup sequence
__device__ __forceinline__ float fsqrt(float x) {
    return __builtin_amdgcn_sqrtf(x);
}

__global__ __launch_bounds__(256) void add_loss_stage1(
    const float* __restrict__ pred_r,   // (B,4)
    const float* __restrict__ pred_t,   // (B,3)
    const float* __restrict__ gt_r,     // (B,4)
    const float* __restrict__ gt_t,     // (B,3)
    const int*   __restrict__ obj_ids,  // (B,)
    const float* __restrict__ points,   // (NOBJ, NPTS, 3)
    float* __restrict__ partial)        // (NBLK,)
{
    const int wave  = threadIdx.x >> 6;
    const int lane  = threadIdx.x & 63;
    const int gwave = blockIdx.x * WPB + wave;
    const int b0    = gwave * EPW;

    // ---- packed (elem0, elem1) quaternion -> D = Rp - Rg, via v_pk_*_f32 ----
    const float4 qp0 = ((const float4*)pred_r)[b0 + 0];
    const float4 qp1 = ((const float4*)pred_r)[b0 + 1];
    const float4 qg0 = ((const float4*)gt_r)[b0 + 0];
    const float4 qg1 = ((const float4*)gt_r)[b0 + 1];

    v2f pw = {qp0.x, qp1.x}, px = {qp0.y, qp1.y}, py = {qp0.z, qp1.z}, pz = {qp0.w, qp1.w};
    v2f gw = {qg0.x, qg1.x}, gx = {qg0.y, qg1.y}, gy = {qg0.z, qg1.z}, gz = {qg0.w, qg1.w};

    v2f d00 = 2.f*((gy*gy + gz*gz) - (py*py + pz*pz));
    v2f d01 = 2.f*((px*py - pw*pz) - (gx*gy - gw*gz));
    v2f d02 = 2.f*((px*pz + pw*py) - (gx*gz + gw*gy));
    v2f d10 = 2.f*((px*py + pw*pz) - (gx*gy + gw*gz));
    v2f d11 = 2.f*((gx*gx + gz*gz) - (px*px + pz*pz));
    v2f d12 = 2.f*((py*pz - pw*px) - (gy*gz - gw*gx));
    v2f d20 = 2.f*((px*pz - pw*py) - (gx*gz - gw*gy));
    v2f d21 = 2.f*((py*pz + pw*px) - (gy*gz + gw*gx));
    v2f d22 = 2.f*((gx*gx + gy*gy) - (px*px + py*py));

    // ---- packed t-diff: 6 consecutive floats per array, float2 loads ----
    // byte offset = 12*b0 = 24*gwave -> 8B aligned
    const float2* PT2 = (const float2*)(pred_t + 3*b0);
    const float2* GT2 = (const float2*)(gt_t  + 3*b0);
    float2 ta = PT2[0], tb = PT2[1], tc = PT2[2];
    float2 ua = GT2[0], ub = GT2[1], uc = GT2[2];
    v2f tdx = { ta.x - ua.x, tb.y - ub.y };
    v2f tdy = { ta.y - ua.y, tc.x - uc.x };
    v2f tdz = { tb.x - ub.x, tc.y - uc.y };

    v2f tq = tdx*tdx + tdy*tdy + tdz*tdz;
    const float acc_trans = fsqrt(tq.x) + fsqrt(tq.y);

    const int obj0 = obj_ids[b0 + 0];
    const int obj1 = obj_ids[b0 + 1];

    // two independent packed accumulator chains (shorter v_pk_add dep chain)
    v2f sacc0 = {0.f, 0.f};
    v2f sacc1 = {0.f, 0.f};

    #pragma unroll
    for (int e = 0; e < EPW; ++e) {
        const float D00 = d00[e], D01 = d01[e], D02 = d02[e];
        const float D10 = d10[e], D11 = d11[e], D12 = d12[e];
        const float D20 = d20[e], D21 = d21[e], D22 = d22[e];
        const float TX = tdx[e], TY = tdy[e], TZ = tdz[e];
        const int obj = e ? obj1 : obj0;
        // object row = 1500 floats = 6000 B (16-divisible -> float4-aligned)
        const float4* __restrict__ P4 = (const float4*)(points + (size_t)obj * (NPTS*3));

        // 500 points = 125 groups of 4 points (3 float4 per group)
        #pragma unroll
        for (int t = 0; t < 2; ++t) {
            const int g = t*64 + lane;
            if (t == 0 || lane < 61) {
                float4 a  = P4[3*g+0];
                float4 b4 = P4[3*g+1];
                float4 c  = P4[3*g+2];
                // pair 0 = points {0,1}, pair 1 = points {2,3} of the group
                v2f xs[2] = { {a.x, a.w},  {b4.z, c.y} };
                v2f ys[2] = { {a.y, b4.x}, {b4.w, c.z} };
                v2f zs[2] = { {a.z, b4.y}, {c.x, c.w} };
                #pragma unroll
                for (int j = 0; j < 2; ++j) {
                    v2f x = xs[j], y = ys[j], z = zs[j];
                    v2f vx = D00*x + D01*y + D02*z;
                    v2f vy = D10*x + D11*y + D12*z;
                    v2f vz = D20*x + D21*y + D22*z;
                    v2f r  = vx*vx + vy*vy + vz*vz;
                    r.x = fsqrt(r.x); r.y = fsqrt(r.y);
                    sacc0 += r;                         // v_pk_add_f32
                    v2f ax = vx + TX, ay = vy + TY, az = vz + TZ;
                    v2f r2 = ax*ax + ay*ay + az*az;
                    r2.x = fsqrt(r2.x); r2.y = fsqrt(r2.y);
                    sacc1 += r2;                        // v_pk_add_f32
                }
            }
        }
    }

    v2f sacc = sacc0 + sacc1;
    float acc_pts = sacc.x + sacc.y;
    #pragma unroll
    for (int off = 32; off > 0; off >>= 1)
        acc_pts += __shfl_down(acc_pts, off, 64);

    __shared__ float red[WPB];
    if (lane == 0)
        red[wave] = acc_pts * (1.0f / NPTS) + acc_trans;
    __syncthreads();
    if (threadIdx.x == 0)
        partial[blockIdx.x] = red[0] + red[1] + red[2] + red[3];  // plain store, no atomics
}

__global__ __launch_bounds__(256) void add_loss_stage2(
    const float* __restrict__ partial,  // (NBLK,)
    float* __restrict__ out)            // scalar
{
    const int wave = threadIdx.x >> 6;
    const int lane = threadIdx.x & 63;

    float s = 0.0f;
    #pragma unroll
    for (int k = 0; k < NBLK / 256; ++k)
        s += partial[k * 256 + threadIdx.x];

    #pragma unroll
    for (int off = 32; off > 0; off >>= 1)
        s += __shfl_down(s, off, 64);

    __shared__ float red[4];
    if (lane == 0) red[wave] = s;
    __syncthreads();
    if (threadIdx.x == 0)
        out[0] = (red[0] + red[1] + red[2] + red[3]) * (1.0f / BATCH);
}

extern "C" void kernel_launch(void* const* d_in, const int* in_sizes, int n_in,
                              void* d_out, int out_size, void* d_ws, size_t ws_size,
                              hipStream_t stream) {
    const float* pred_r  = (const float*)d_in[0];
    const float* pred_t  = (const float*)d_in[1];
    const float* gt_r    = (const float*)d_in[2];
    const float* gt_t    = (const float*)d_in[3];
    const int*   obj_ids = (const int*)d_in[4];
    const float* points  = (const float*)d_in[5];
    float* out     = (float*)d_out;
    float* partial = (float*)d_ws;      // 2048 floats = 8 KB of scratch

    add_loss_stage1<<<NBLK, 256, 0, stream>>>(
        pred_r, pred_t, gt_r, gt_t, obj_ids, points, partial);
    add_loss_stage2<<<1, 256, 0, stream>>>(partial, out);
}